// Round 2
// baseline (30.484 us; speedup 1.0000x reference)
//
#include <hip/hip_runtime.h>

// NuFACoef: out[b] = sum_{i,j} coef[i][j] * trace_ij / 16^(i+j+2),
// trace_ij = sum_k colsum(x^(i+2))[k]^(j+1); colsum chain u_{m+1} = u_m @ x.
// One wave per TWO batches: all 32 float4-loads issued up front so memory
// demand covers both compute phases (fixes bursty-demand latency gap).
// Lane layout per batch: rows 16*rg+k (k=0..15), cols 4*cg..4*cg+3.

__device__ __forceinline__ float4 xor_reduce_rg(float4 v) {
    v.x += __shfl_xor(v.x, 16, 64); v.y += __shfl_xor(v.y, 16, 64);
    v.z += __shfl_xor(v.z, 16, 64); v.w += __shfl_xor(v.w, 16, 64);
    v.x += __shfl_xor(v.x, 32, 64); v.y += __shfl_xor(v.y, 32, 64);
    v.z += __shfl_xor(v.z, 32, 64); v.w += __shfl_xor(v.w, 32, 64);
    return v;
}

__device__ __forceinline__ float compute_batch(const float4 xr[16],
                                               const float cs[4][4], int rg) {
    // u1 = colsum(x)
    float4 u = xr[0];
    #pragma unroll
    for (int k = 1; k < 16; ++k) {
        u.x += xr[k].x; u.y += xr[k].y; u.z += xr[k].z; u.w += xr[k].w;
    }
    u = xor_reduce_rg(u);

    float contrib = 0.f;
    #pragma unroll
    for (int m = 0; m < 4; ++m) {
        // u_new[c] = sum_i u[i]*x[i][c]; lane covers rows 16*rg..16*rg+15.
        // u[i] lives as component i&3 on any lane with cg = i>>2.
        float4 acc = {0.f, 0.f, 0.f, 0.f};
        #pragma unroll
        for (int k = 0; k < 16; ++k) {
            const int src = 4 * rg + (k >> 2);
            const float uk = ((k & 3) == 0) ? __shfl(u.x, src, 64)
                           : ((k & 3) == 1) ? __shfl(u.y, src, 64)
                           : ((k & 3) == 2) ? __shfl(u.z, src, 64)
                           :                  __shfl(u.w, src, 64);
            acc.x += uk * xr[k].x; acc.y += uk * xr[k].y;
            acc.z += uk * xr[k].z; acc.w += uk * xr[k].w;
        }
        u = xor_reduce_rg(acc);   // colsum(x^(m+2)), duplicated across rgs

        #pragma unroll
        for (int c = 0; c < 4; ++c) {
            const float v1 = (c == 0) ? u.x : (c == 1) ? u.y : (c == 2) ? u.z : u.w;
            const float v2 = v1 * v1;
            const float v3 = v2 * v1;
            const float v4 = v2 * v2;
            contrib += cs[m][0] * v1 + cs[m][1] * v2 + cs[m][2] * v3 + cs[m][3] * v4;
        }
    }
    return contrib;   // identical across rg groups; summed over this lane's 4 cols
}

__global__ __launch_bounds__(256) void nufa_kernel(
    const float* __restrict__ x, const float* __restrict__ coef,
    float* __restrict__ out, int B)
{
    const int wave = threadIdx.x >> 6;
    const int lane = threadIdx.x & 63;
    const int b0 = (blockIdx.x * 4 + wave) * 2;   // two consecutive batches
    if (b0 >= B) return;

    const int rg = lane >> 4;
    const int cg = lane & 15;

    const float4* base = reinterpret_cast<const float4*>(x)
                         + (size_t)b0 * 1024 + 256 * rg + cg;
    float4 A[16], Bv[16];
    #pragma unroll
    for (int k = 0; k < 16; ++k) A[k]  = base[16 * k];
    #pragma unroll
    for (int k = 0; k < 16; ++k) Bv[k] = base[1024 + 16 * k];

    // cs[i][j] = coef[i][j] / 16^(i+j+2)  (uniform -> SGPRs)
    float cs[4][4];
    #pragma unroll
    for (int i = 0; i < 4; ++i)
        #pragma unroll
        for (int j = 0; j < 4; ++j)
            cs[i][j] = coef[i * 4 + j] * (1.0f / (float)(1ull << (4 * (i + j + 2))));

    float ca = compute_batch(A,  cs, rg);
    float cb = compute_batch(Bv, cs, rg);

    // contrib already duplicated across rg; reduce over the 16 cg lanes only.
    #pragma unroll
    for (int d = 1; d < 16; d <<= 1) {
        ca += __shfl_xor(ca, d, 64);
        cb += __shfl_xor(cb, d, 64);
    }
    if (lane == 0) { out[b0] = ca; out[b0 + 1] = cb; }
}

extern "C" void kernel_launch(void* const* d_in, const int* in_sizes, int n_in,
                              void* d_out, int out_size, void* d_ws, size_t ws_size,
                              hipStream_t stream) {
    const float* x    = (const float*)d_in[0];
    const float* coef = (const float*)d_in[1];
    float* out        = (float*)d_out;
    const int B = in_sizes[0] / 4096;              // 64*64 per batch
    const int wavesNeeded = (B + 1) / 2;           // 2 batches per wave
    const int blocks = (wavesNeeded + 3) / 4;      // 4 waves per block
    nufa_kernel<<<blocks, 256, 0, stream>>>(x, coef, out, B);
}

// Round 3
// 29.984 us; speedup vs baseline: 1.0167x; 1.0167x over previous
//
#include <hip/hip_runtime.h>

// NuFACoef: out[b] = sum_{i,j} coef[i][j] * trace_ij / 16^(i+j+2),
// trace_ij = sum_k colsum(x^(i+2))[k]^(j+1); colsum chain u_{m+1} = u_m @ x.
//
// R3: one batch per 2-wave block (128 thr). Each wave owns 32 rows; lane owns
// 8 rows x 4 cols = 32 VGPRs of data -> total ~60 VGPR -> 8 waves/SIMD
// (launch_bounds(128,8)). Cross-wave colsum combine via ping-pong LDS
// (1 barrier/step). Shorter dependent chain + 1.6x occupancy vs R1.

__device__ __forceinline__ float4 xor_reduce_rg(float4 v) {
    v.x += __shfl_xor(v.x, 16, 64); v.y += __shfl_xor(v.y, 16, 64);
    v.z += __shfl_xor(v.z, 16, 64); v.w += __shfl_xor(v.w, 16, 64);
    v.x += __shfl_xor(v.x, 32, 64); v.y += __shfl_xor(v.y, 32, 64);
    v.z += __shfl_xor(v.z, 32, 64); v.w += __shfl_xor(v.w, 32, 64);
    return v;
}

__global__ __launch_bounds__(128, 8) void nufa_kernel(
    const float* __restrict__ x, const float* __restrict__ coef,
    float* __restrict__ out)
{
    const int w    = threadIdx.x >> 6;   // wave 0/1: rows 32w..32w+31
    const int lane = threadIdx.x & 63;
    const int b    = blockIdx.x;
    const int rg   = lane >> 4;          // lane rows: 32w + 8rg + k, k=0..7
    const int cg   = lane & 15;          // cols 4cg..4cg+3

    __shared__ float4 part[2][2][16];    // [pingpong][wave][cg]

    // f4 index = row*16 + cg; base row = 32w + 8rg.
    const float4* base = reinterpret_cast<const float4*>(x)
                         + (size_t)b * 1024 + 512 * w + 128 * rg + cg;
    float4 xr[8];
    #pragma unroll
    for (int k = 0; k < 8; ++k) xr[k] = base[16 * k];

    // cs[i][j] = coef[i][j] / 16^(i+j+2) (uniform -> scalar loads)
    float cs[4][4];
    #pragma unroll
    for (int i = 0; i < 4; ++i)
        #pragma unroll
        for (int j = 0; j < 4; ++j)
            cs[i][j] = coef[i * 4 + j] * (1.0f / (float)(1ull << (4 * (i + j + 2))));

    // u1 partial over this wave's 32 rows
    float4 s = xr[0];
    #pragma unroll
    for (int k = 1; k < 8; ++k) {
        s.x += xr[k].x; s.y += xr[k].y; s.z += xr[k].z; s.w += xr[k].w;
    }
    s = xor_reduce_rg(s);

    int buf = 0;
    if (rg == 0) part[buf][w][cg] = s;
    __syncthreads();
    float4 u;
    {
        const float4 a0 = part[buf][0][cg], a1 = part[buf][1][cg];
        u.x = a0.x + a1.x; u.y = a0.y + a1.y; u.z = a0.z + a1.z; u.w = a0.w + a1.w;
    }
    buf ^= 1;

    float contrib = 0.f;
    #pragma unroll
    for (int m = 0; m < 4; ++m) {
        // acc[c] += u[i] * x[i][c] over this lane's rows i = 32w+8rg+k.
        // u[i]: component (i&3)=(k&3), source lane (i>>2) = 8w + 2rg + (k>>2).
        float4 acc = {0.f, 0.f, 0.f, 0.f};
        #pragma unroll
        for (int k = 0; k < 8; ++k) {
            const int src = 8 * w + 2 * rg + (k >> 2);
            const float uk = ((k & 3) == 0) ? __shfl(u.x, src, 64)
                           : ((k & 3) == 1) ? __shfl(u.y, src, 64)
                           : ((k & 3) == 2) ? __shfl(u.z, src, 64)
                           :                  __shfl(u.w, src, 64);
            acc.x += uk * xr[k].x; acc.y += uk * xr[k].y;
            acc.z += uk * xr[k].z; acc.w += uk * xr[k].w;
        }
        acc = xor_reduce_rg(acc);                 // wave-partial colsum
        if (rg == 0) part[buf][w][cg] = acc;
        __syncthreads();
        const float4 a0 = part[buf][0][cg], a1 = part[buf][1][cg];
        u.x = a0.x + a1.x; u.y = a0.y + a1.y; u.z = a0.z + a1.z; u.w = a0.w + a1.w;
        buf ^= 1;

        // trace terms over this lane's 4 columns
        #pragma unroll
        for (int c = 0; c < 4; ++c) {
            const float v1 = (c == 0) ? u.x : (c == 1) ? u.y : (c == 2) ? u.z : u.w;
            const float v2 = v1 * v1;
            const float v3 = v2 * v1;
            const float v4 = v2 * v2;
            contrib += cs[m][0] * v1 + cs[m][1] * v2 + cs[m][2] * v3 + cs[m][3] * v4;
        }
    }

    // contrib depends only on cg (u identical everywhere): reduce the 16 cg
    // lanes of wave 0 and write.
    #pragma unroll
    for (int d = 1; d < 16; d <<= 1) contrib += __shfl_xor(contrib, d, 64);
    if (threadIdx.x == 0) out[b] = contrib;
}

extern "C" void kernel_launch(void* const* d_in, const int* in_sizes, int n_in,
                              void* d_out, int out_size, void* d_ws, size_t ws_size,
                              hipStream_t stream) {
    const float* x    = (const float*)d_in[0];
    const float* coef = (const float*)d_in[1];
    float* out        = (float*)d_out;
    const int B = in_sizes[0] / 4096;   // 64*64 per batch
    nufa_kernel<<<B, 128, 0, stream>>>(x, coef, out);
}